// Round 1
// baseline (103.121 us; speedup 1.0000x reference)
//
#include <hip/hip_runtime.h>
#include <hip/hip_bf16.h>
#include <cstdint>

#define HDIM 2048
#define INDIM 4096
#define CDIM 4096
#define KDIM 2048   // GEMM K = hidden size

typedef __attribute__((ext_vector_type(8))) short short8;
typedef __attribute__((ext_vector_type(4))) float f32x4;

__device__ __forceinline__ unsigned short f2bf(float f) {
  uint32_t u = __float_as_uint(f);
  u = (u + 0x7FFFu + ((u >> 16) & 1u)) >> 16;
  return (unsigned short)u;
}

__device__ __forceinline__ void gload16(const void* g, void* l) {
  __builtin_amdgcn_global_load_lds(
      (const __attribute__((address_space(1))) void*)g,
      (__attribute__((address_space(3))) void*)l, 16, 0, 0);
}

// ---------------- Kernel 1: fp32 -> bf16 convert (c_input and aW_hh) ----------
__global__ __launch_bounds__(256) void k_convert(
    const float* __restrict__ c_input, const float* __restrict__ aW_hh,
    unsigned short* __restrict__ cbf, unsigned short* __restrict__ wbf) {
  int i = blockIdx.x * 256 + threadIdx.x;  // vec4 index, 0..3145727
  const float4* src;
  unsigned short* dst;
  int off;
  const int NCVEC = CDIM * HDIM / 4;  // 2097152
  if (i < NCVEC) { src = (const float4*)c_input; dst = cbf; off = i; }
  else           { src = (const float4*)aW_hh;  dst = wbf; off = i - NCVEC; }
  float4 v = src[off];
  ushort4 o;
  o.x = f2bf(v.x); o.y = f2bf(v.y); o.z = f2bf(v.z); o.w = f2bf(v.w);
  *(ushort4*)(dst + (size_t)off * 4) = o;
}

// ---------------- Kernel 2: GEMVs for gates (i,o,g) and x-projection ----------
// virtual row vr: [0,2048)=i sigmoid, [2048,4096)=o sigmoid, [4096,6144)=g tanh,
// [6144,8192)=xa2 = x@aW_ih.T + ab_ih + ab_hh  (f gate is dead code -> skipped)
__global__ __launch_bounds__(256) void k_gemv(
    const float* __restrict__ x, const float* __restrict__ h0,
    const float* __restrict__ W_ih, const float* __restrict__ b_ih,
    const float* __restrict__ W_hh, const float* __restrict__ b_hh,
    const float* __restrict__ aW_ih, const float* __restrict__ ab_ih,
    const float* __restrict__ ab_hh,
    float* __restrict__ i_sig, float* __restrict__ o_sig,
    float* __restrict__ g_tanh, float* __restrict__ xa2) {
  const int wid = threadIdx.x >> 6, lane = threadIdx.x & 63;
  const int vr = blockIdx.x * 4 + wid;
  const int typ = vr >> 11;
  const int h = vr & (HDIM - 1);
  float sum = 0.f;
  if (typ < 3) {
    const int grow = (typ == 0) ? h : (typ == 1) ? (2 * HDIM + h) : (3 * HDIM + h);
    const float4* wr4 = (const float4*)(W_ih + (size_t)grow * INDIM);
    const float4* x4 = (const float4*)x;
#pragma unroll
    for (int it = 0; it < INDIM / 256; ++it) {  // 16
      float4 w = wr4[it * 64 + lane], xv = x4[it * 64 + lane];
      sum += w.x * xv.x + w.y * xv.y + w.z * xv.z + w.w * xv.w;
    }
    const float4* wh4 = (const float4*)(W_hh + (size_t)grow * HDIM);
    const float4* h4 = (const float4*)h0;
#pragma unroll
    for (int it = 0; it < HDIM / 256; ++it) {  // 8
      float4 w = wh4[it * 64 + lane], hv = h4[it * 64 + lane];
      sum += w.x * hv.x + w.y * hv.y + w.z * hv.z + w.w * hv.w;
    }
#pragma unroll
    for (int off = 32; off > 0; off >>= 1) sum += __shfl_down(sum, off);
    if (lane == 0) {
      float z = sum + b_ih[grow] + b_hh[grow];
      if (typ == 0)      i_sig[h] = 1.f / (1.f + expf(-z));
      else if (typ == 1) o_sig[h] = 1.f / (1.f + expf(-z));
      else               g_tanh[h] = tanhf(z);
    }
  } else {
    const float4* wr4 = (const float4*)(aW_ih + (size_t)h * INDIM);
    const float4* x4 = (const float4*)x;
#pragma unroll
    for (int it = 0; it < INDIM / 256; ++it) {
      float4 w = wr4[it * 64 + lane], xv = x4[it * 64 + lane];
      sum += w.x * xv.x + w.y * xv.y + w.z * xv.z + w.w * xv.w;
    }
#pragma unroll
    for (int off = 32; off > 0; off >>= 1) sum += __shfl_down(sum, off);
    if (lane == 0) xa2[h] = sum + ab_ih[h] + ab_hh[h];
  }
}

// ---------------- Kernel 3: bf16 MFMA GEMM + fused sigmoid/exp/column-reduce --
// alpha_pre[j][h] = sum_k c_input[j][k] * aW_hh[h][k]   (A,B both row-major-K)
// epilogue: e = exp(sigmoid(alpha_pre + xa2[h])); atomically accumulate
//   acc_se[h] += e ; acc_sce[h] += c_input_f32[j][h] * e
// 128x128 tile, BK=32, 4 waves (2x2 of 64x64), 16x16x32 MFMA.
// LDS XOR swizzle: phys_col_byte = col_byte ^ (((row>>1)&3)<<4) — applied on the
// pre-swizzled global source (gload_lds writes linearly) and on the ds_read.
__global__ __launch_bounds__(256) void k_gemm(
    const unsigned short* __restrict__ A, const unsigned short* __restrict__ B,
    const float* __restrict__ c_in, const float* __restrict__ xa2,
    float* __restrict__ acc_se, float* __restrict__ acc_sce) {
  __shared__ unsigned short As[4096];  // 128 rows x 32 k (8 KB)
  __shared__ unsigned short Bs[4096];
  const int t = threadIdx.x;
  const int lane = t & 63, wid = t >> 6;
  const int wr = wid >> 1, wc = wid & 1;
  const int l15 = lane & 15, l4 = lane >> 4;
  const int bm = blockIdx.x & 31, bn = blockIdx.x >> 5;
  const int m0 = bm * 128, n0 = bn * 128;

  f32x4 acc[4][4] = {};

  // staging: 2 x 16B per thread per matrix; dest LDS byte = q*4096 + t*16
  const int beta0 = t * 16;
  const int row0 = beta0 >> 6;
  const int colb0 = (beta0 & 63) ^ (((row0 >> 1) & 3) << 4);
  const int beta1 = 4096 + t * 16;
  const int row1 = beta1 >> 6;
  const int colb1 = (beta1 & 63) ^ (((row1 >> 1) & 3) << 4);
  const char* Ab = (const char*)A;
  const char* Bb = (const char*)B;

  for (int k0 = 0; k0 < KDIM; k0 += 32) {
    gload16(Ab + ((size_t)(m0 + row0) * KDIM + k0) * 2 + colb0, (char*)As + beta0);
    gload16(Ab + ((size_t)(m0 + row1) * KDIM + k0) * 2 + colb1, (char*)As + beta1);
    gload16(Bb + ((size_t)(n0 + row0) * KDIM + k0) * 2 + colb0, (char*)Bs + beta0);
    gload16(Bb + ((size_t)(n0 + row1) * KDIM + k0) * 2 + colb1, (char*)Bs + beta1);
    __syncthreads();
    short8 af[4], bfr[4];
#pragma unroll
    for (int m = 0; m < 4; ++m) {
      int r = wr * 64 + m * 16 + l15;
      int cb = (l4 * 16) ^ (((r >> 1) & 3) << 4);
      af[m] = *(const short8*)((const char*)As + r * 64 + cb);
    }
#pragma unroll
    for (int n = 0; n < 4; ++n) {
      int r = wc * 64 + n * 16 + l15;
      int cb = (l4 * 16) ^ (((r >> 1) & 3) << 4);
      bfr[n] = *(const short8*)((const char*)Bs + r * 64 + cb);
    }
#pragma unroll
    for (int m = 0; m < 4; ++m)
#pragma unroll
      for (int n = 0; n < 4; ++n)
        acc[m][n] = __builtin_amdgcn_mfma_f32_16x16x32_bf16(af[m], bfr[n], acc[m][n], 0, 0, 0);
    __syncthreads();
  }

  // epilogue: D layout col = lane&15, row = (lane>>4)*4 + reg  [m89-verified]
#pragma unroll
  for (int n = 0; n < 4; ++n) {
    const int hcol = n0 + wc * 64 + n * 16 + l15;
    const float xa = xa2[hcol];
    float se = 0.f, sce = 0.f;
#pragma unroll
    for (int m = 0; m < 4; ++m) {
      const int jbase = m0 + wr * 64 + m * 16 + l4 * 4;
#pragma unroll
      for (int r = 0; r < 4; ++r) {
        float z = acc[m][n][r] + xa;
        float s = 1.f / (1.f + __expf(-z));
        float e = __expf(s);
        se += e;
        sce += c_in[(size_t)(jbase + r) * HDIM + hcol] * e;
      }
    }
    se += __shfl_xor(se, 16); se += __shfl_xor(se, 32);
    sce += __shfl_xor(sce, 16); sce += __shfl_xor(sce, 32);
    if (l4 == 0) {
      atomicAdd(&acc_se[hcol], se);
      atomicAdd(&acc_sce[hcol], sce);
    }
  }
}

// ---------------- Kernel 4: finalize ------------------------------------------
__global__ __launch_bounds__(256) void k_final(
    const float* __restrict__ i_sig, const float* __restrict__ o_sig,
    const float* __restrict__ g_tanh, const float* __restrict__ acc_se,
    const float* __restrict__ acc_sce, float* __restrict__ out) {
  int h = blockIdx.x * 256 + threadIdx.x;
  if (h >= HDIM) return;
  float wi = expf(i_sig[h]);
  float tot = acc_se[h] + wi;
  float c1 = (acc_sce[h] + g_tanh[h] * wi) / tot;
  float h1 = o_sig[h] * tanhf(c1);
  out[h] = h1;
  out[HDIM + h] = c1;
}

extern "C" void kernel_launch(void* const* d_in, const int* in_sizes, int n_in,
                              void* d_out, int out_size, void* d_ws, size_t ws_size,
                              hipStream_t stream) {
  const float* x     = (const float*)d_in[0];
  const float* c_inp = (const float*)d_in[1];
  const float* h0    = (const float*)d_in[2];
  // d_in[3] = c0: unused by the reference output
  const float* W_ih  = (const float*)d_in[4];
  const float* b_ih  = (const float*)d_in[5];
  const float* W_hh  = (const float*)d_in[6];
  const float* b_hh  = (const float*)d_in[7];
  const float* aW_ih = (const float*)d_in[8];
  const float* ab_ih = (const float*)d_in[9];
  const float* aW_hh = (const float*)d_in[10];
  const float* ab_hh = (const float*)d_in[11];
  float* out = (float*)d_out;

  char* ws = (char*)d_ws;
  unsigned short* cbf = (unsigned short*)ws;                         // 16 MB
  unsigned short* wbf = (unsigned short*)(ws + (size_t)CDIM * HDIM * 2);  // 8 MB
  char* p = ws + (size_t)CDIM * HDIM * 2 + (size_t)HDIM * KDIM * 2;
  float* i_sig  = (float*)p; p += HDIM * 4;
  float* o_sig  = (float*)p; p += HDIM * 4;
  float* g_tanh = (float*)p; p += HDIM * 4;
  float* xa2    = (float*)p; p += HDIM * 4;
  float* acc_se = (float*)p; p += HDIM * 4;
  float* acc_sce = (float*)p;

  // zero the atomic accumulators every launch (graph-capturable)
  hipMemsetAsync(acc_se, 0, 2 * HDIM * sizeof(float), stream);

  k_convert<<<(CDIM * HDIM + HDIM * KDIM) / 4 / 256, 256, 0, stream>>>(c_inp, aW_hh, cbf, wbf);
  k_gemv<<<4 * HDIM / 4, 256, 0, stream>>>(x, h0, W_ih, b_ih, W_hh, b_hh,
                                           aW_ih, ab_ih, ab_hh,
                                           i_sig, o_sig, g_tanh, xa2);
  k_gemm<<<(CDIM / 128) * (KDIM / 128), 256, 0, stream>>>(cbf, wbf, c_inp, xa2,
                                                          acc_se, acc_sce);
  k_final<<<(HDIM + 255) / 256, 256, 0, stream>>>(i_sig, o_sig, g_tanh,
                                                  acc_se, acc_sce, out);
}

// Round 3
// 72.399 us; speedup vs baseline: 1.4243x; 1.4243x over previous
//
#include <hip/hip_runtime.h>
#include <hip/hip_bf16.h>
#include <cstdint>

#define HDIM 2048
#define INDIM 4096
#define CDIM 4096
#define KDIM 2048   // GEMM K = hidden size

typedef __attribute__((ext_vector_type(4))) int int4v;

__device__ __forceinline__ void gload16(const void* g, void* l) {
  __builtin_amdgcn_global_load_lds(
      (const __attribute__((address_space(1))) void*)g,
      (__attribute__((address_space(3))) void*)l, 16, 0, 0);
}

// ---------------- Kernel 1: prep = i8 row-quant (c_input, aW_hh) + GEMVs ------
// blocks [0,6144): one block per row; quantize 2048 f32 -> i8 with per-row
//   absmax scale (exact-absolute error model: eps_rms = rowmax/127/sqrt(12)).
// blocks [6144,8192): GEMV virtual rows: i/o/g gates + x-projection
//   (f gate is dead code -> skipped).
__global__ __launch_bounds__(256) void k_prep(
    const float* __restrict__ c_input, const float* __restrict__ aW_hh,
    int8_t* __restrict__ a8, int8_t* __restrict__ b8,
    float* __restrict__ dAs, float* __restrict__ dBs,
    const float* __restrict__ x, const float* __restrict__ h0,
    const float* __restrict__ W_ih, const float* __restrict__ b_ih,
    const float* __restrict__ W_hh, const float* __restrict__ b_hh,
    const float* __restrict__ aW_ih, const float* __restrict__ ab_ih,
    const float* __restrict__ ab_hh,
    float* __restrict__ i_sig, float* __restrict__ o_sig,
    float* __restrict__ g_tanh, float* __restrict__ xa2,
    float* __restrict__ accz) {
  const int t = threadIdx.x;
  const int wid = t >> 6, lane = t & 63;

  if (blockIdx.x < CDIM + HDIM) {
    // ---- i8 row quantization ----
    if (blockIdx.x == 0) {
#pragma unroll
      for (int i = 0; i < 16; ++i) accz[i * 256 + t] = 0.f;
    }
    const int row = blockIdx.x;
    const float* src; int8_t* dst; float* dsc; int r;
    if (row < CDIM) { src = c_input; dst = a8; dsc = dAs; r = row; }
    else            { src = aW_hh;  dst = b8; dsc = dBs; r = row - CDIM; }
    const float4* s4 = (const float4*)(src + (size_t)r * KDIM);
    const float4 v0 = s4[t * 2], v1 = s4[t * 2 + 1];
    float am = fmaxf(fmaxf(fmaxf(fabsf(v0.x), fabsf(v0.y)),
                           fmaxf(fabsf(v0.z), fabsf(v0.w))),
                     fmaxf(fmaxf(fabsf(v1.x), fabsf(v1.y)),
                           fmaxf(fabsf(v1.z), fabsf(v1.w))));
#pragma unroll
    for (int off = 32; off > 0; off >>= 1) am = fmaxf(am, __shfl_xor(am, off));
    __shared__ float wmax[4];
    if (lane == 0) wmax[wid] = am;
    __syncthreads();
    am = fmaxf(fmaxf(wmax[0], wmax[1]), fmaxf(wmax[2], wmax[3]));
    am = fmaxf(am, 1e-20f);
    const float inv = 127.0f / am;
    const float vv[8] = {v0.x, v0.y, v0.z, v0.w, v1.x, v1.y, v1.z, v1.w};
    uint32_t p0 = 0, p1 = 0;
#pragma unroll
    for (int i = 0; i < 4; ++i)
      p0 |= (uint32_t)(__float2int_rn(vv[i] * inv) & 0xFF) << (i * 8);
#pragma unroll
    for (int i = 0; i < 4; ++i)
      p1 |= (uint32_t)(__float2int_rn(vv[4 + i] * inv) & 0xFF) << (i * 8);
    *(uint2*)(dst + (size_t)r * KDIM + t * 8) = make_uint2(p0, p1);
    if (t == 0) dsc[r] = am * (1.0f / 127.0f);
    return;
  }

  // ---- GEMV part ----
  const int vr = (blockIdx.x - (CDIM + HDIM)) * 4 + wid;
  const int typ = vr >> 11;
  const int h = vr & (HDIM - 1);
  float sum = 0.f;
  if (typ < 3) {
    const int grow = (typ == 0) ? h : (typ == 1) ? (2 * HDIM + h) : (3 * HDIM + h);
    const float4* wr4 = (const float4*)(W_ih + (size_t)grow * INDIM);
    const float4* x4 = (const float4*)x;
#pragma unroll
    for (int it = 0; it < INDIM / 256; ++it) {  // 16
      float4 w = wr4[it * 64 + lane], xv = x4[it * 64 + lane];
      sum += w.x * xv.x + w.y * xv.y + w.z * xv.z + w.w * xv.w;
    }
    const float4* wh4 = (const float4*)(W_hh + (size_t)grow * HDIM);
    const float4* h4 = (const float4*)h0;
#pragma unroll
    for (int it = 0; it < HDIM / 256; ++it) {  // 8
      float4 w = wh4[it * 64 + lane], hv = h4[it * 64 + lane];
      sum += w.x * hv.x + w.y * hv.y + w.z * hv.z + w.w * hv.w;
    }
#pragma unroll
    for (int off = 32; off > 0; off >>= 1) sum += __shfl_down(sum, off);
    if (lane == 0) {
      float z = sum + b_ih[grow] + b_hh[grow];
      if (typ == 0)      i_sig[h] = 1.f / (1.f + expf(-z));
      else if (typ == 1) o_sig[h] = 1.f / (1.f + expf(-z));
      else               g_tanh[h] = tanhf(z);
    }
  } else {
    const float4* wr4 = (const float4*)(aW_ih + (size_t)h * INDIM);
    const float4* x4 = (const float4*)x;
#pragma unroll
    for (int it = 0; it < INDIM / 256; ++it) {
      float4 w = wr4[it * 64 + lane], xv = x4[it * 64 + lane];
      sum += w.x * xv.x + w.y * xv.y + w.z * xv.z + w.w * xv.w;
    }
#pragma unroll
    for (int off = 32; off > 0; off >>= 1) sum += __shfl_down(sum, off);
    if (lane == 0) xa2[h] = sum + ab_ih[h] + ab_hh[h];
  }
}

// ---------------- Kernel 2: i8 MFMA GEMM + fused sigmoid/exp/col-reduce -------
// alpha_pre[j][h] = dA[j]*dB[h] * sum_k qa[j][k]*qb[h][k]  (i32 exact accum).
// Per-row scales factor out of the dot -> result invariant to any MFMA k-layout
// permutation (A and B loaded symmetrically).
// 128x128 tile, BK=128 bytes, 4 waves (2x2 of 64x64), mfma_i32_16x16x64_i8 x2.
// LDS swizzle (rule #21): linear gload_lds dest, source col pre-XORed with
// ((row&7)<<4), ds_read applies the same XOR -> conflict-free-ish (2-way max).
__global__ __launch_bounds__(256) void k_gemm_i8(
    const int8_t* __restrict__ A, const int8_t* __restrict__ B,
    const float* __restrict__ dAs, const float* __restrict__ dBs,
    const float* __restrict__ c_in, const float* __restrict__ xa2,
    float* __restrict__ acc_se, float* __restrict__ acc_sce) {
  __shared__ uint8_t As[16384];  // 128 rows x 128 k-bytes
  __shared__ uint8_t Bs[16384];
  const int t = threadIdx.x;
  const int lane = t & 63, wid = t >> 6;
  const int wr = wid >> 1, wc = wid & 1;
  const int l15 = lane & 15, l4 = lane >> 4;
  const int bm = blockIdx.x & 31, bn = blockIdx.x >> 5;
  const int m0 = bm * 128, n0 = bn * 128;

  int4v acc[4][4] = {};

  // staging: per matrix 16 KB/step = 4 x 16B per thread.
  // dest byte d = qq*4096 + t*16 -> row = qq*32 + (t>>3), col = (t&7)*16
  const int trow = t >> 3;
  const int tcol = ((t & 7) * 16) ^ ((trow & 7) << 4);  // pre-swizzled source col
  const int8_t* Arow = A + (size_t)(m0 + trow) * KDIM + tcol;
  const int8_t* Brow = B + (size_t)(n0 + trow) * KDIM + tcol;

  for (int k0 = 0; k0 < KDIM; k0 += 128) {
#pragma unroll
    for (int qq = 0; qq < 4; ++qq) {
      gload16(Arow + (size_t)qq * 32 * KDIM + k0, As + qq * 4096 + t * 16);
      gload16(Brow + (size_t)qq * 32 * KDIM + k0, Bs + qq * 4096 + t * 16);
    }
    __syncthreads();
    int4v alo[4], ahi[4], blo[4], bhi[4];
#pragma unroll
    for (int m = 0; m < 4; ++m) {
      const int r = wr * 64 + m * 16 + l15;
      const int swz = (r & 7) << 4;
      alo[m] = *(const int4v*)(As + r * 128 + ((l4 * 16) ^ swz));
      ahi[m] = *(const int4v*)(As + r * 128 + ((64 + l4 * 16) ^ swz));
    }
#pragma unroll
    for (int n = 0; n < 4; ++n) {
      const int r = wc * 64 + n * 16 + l15;
      const int swz = (r & 7) << 4;
      blo[n] = *(const int4v*)(Bs + r * 128 + ((l4 * 16) ^ swz));
      bhi[n] = *(const int4v*)(Bs + r * 128 + ((64 + l4 * 16) ^ swz));
    }
#pragma unroll
    for (int m = 0; m < 4; ++m)
#pragma unroll
      for (int n = 0; n < 4; ++n) {
        acc[m][n] = __builtin_amdgcn_mfma_i32_16x16x64_i8(alo[m], blo[n], acc[m][n], 0, 0, 0);
        acc[m][n] = __builtin_amdgcn_mfma_i32_16x16x64_i8(ahi[m], bhi[n], acc[m][n], 0, 0, 0);
      }
    __syncthreads();
  }

  // epilogue: D layout col = lane&15, row = (lane>>4)*4 + reg  [m89-verified,
  // dtype/shape-independent per m121-m128]
#pragma unroll
  for (int n = 0; n < 4; ++n) {
    const int hcol = n0 + wc * 64 + n * 16 + l15;
    const float xa = xa2[hcol];
    const float db = dBs[hcol];
    float se = 0.f, sce = 0.f;
#pragma unroll
    for (int m = 0; m < 4; ++m) {
      const int jbase = m0 + wr * 64 + m * 16 + l4 * 4;
#pragma unroll
      for (int rr = 0; rr < 4; ++rr) {
        const float sc = dAs[jbase + rr] * db;
        float z = (float)acc[m][n][rr] * sc + xa;
        float s = 1.f / (1.f + __expf(-z));
        float e = __expf(s);
        se += e;
        sce += c_in[(size_t)(jbase + rr) * HDIM + hcol] * e;
      }
    }
    se += __shfl_xor(se, 16); se += __shfl_xor(se, 32);
    sce += __shfl_xor(sce, 16); sce += __shfl_xor(sce, 32);
    if (l4 == 0) {
      atomicAdd(&acc_se[hcol], se);
      atomicAdd(&acc_sce[hcol], sce);
    }
  }
}

// ---------------- Kernel 3: finalize ------------------------------------------
__global__ __launch_bounds__(256) void k_final(
    const float* __restrict__ i_sig, const float* __restrict__ o_sig,
    const float* __restrict__ g_tanh, const float* __restrict__ acc_se,
    const float* __restrict__ acc_sce, float* __restrict__ out) {
  int h = blockIdx.x * 256 + threadIdx.x;
  if (h >= HDIM) return;
  float wi = expf(i_sig[h]);
  float tot = acc_se[h] + wi;
  float c1 = (acc_sce[h] + g_tanh[h] * wi) / tot;
  float h1 = o_sig[h] * tanhf(c1);
  out[h] = h1;
  out[HDIM + h] = c1;
}

extern "C" void kernel_launch(void* const* d_in, const int* in_sizes, int n_in,
                              void* d_out, int out_size, void* d_ws, size_t ws_size,
                              hipStream_t stream) {
  const float* x     = (const float*)d_in[0];
  const float* c_inp = (const float*)d_in[1];
  const float* h0    = (const float*)d_in[2];
  // d_in[3] = c0: unused by the reference output
  const float* W_ih  = (const float*)d_in[4];
  const float* b_ih  = (const float*)d_in[5];
  const float* W_hh  = (const float*)d_in[6];
  const float* b_hh  = (const float*)d_in[7];
  const float* aW_ih = (const float*)d_in[8];
  const float* ab_ih = (const float*)d_in[9];
  const float* aW_hh = (const float*)d_in[10];
  const float* ab_hh = (const float*)d_in[11];
  float* out = (float*)d_out;

  char* ws = (char*)d_ws;
  int8_t* a8 = (int8_t*)ws;                          // 8 MB i8 c_input
  int8_t* b8 = a8 + (size_t)CDIM * KDIM;             // 4 MB i8 aW_hh
  float* dAs = (float*)(b8 + (size_t)HDIM * KDIM);   // 16 KB row scales A
  float* dBs = dAs + CDIM;                           // 8 KB row scales B
  float* fb  = dBs + HDIM;
  float* i_sig   = fb;
  float* o_sig   = fb + HDIM;
  float* g_tanh  = fb + 2 * HDIM;
  float* xa2     = fb + 3 * HDIM;
  float* acc_se  = fb + 4 * HDIM;   // acc_se/acc_sce contiguous: zeroed together
  float* acc_sce = fb + 5 * HDIM;

  k_prep<<<CDIM + HDIM + 4 * HDIM / 4, 256, 0, stream>>>(
      c_inp, aW_hh, a8, b8, dAs, dBs,
      x, h0, W_ih, b_ih, W_hh, b_hh, aW_ih, ab_ih, ab_hh,
      i_sig, o_sig, g_tanh, xa2, acc_se);
  k_gemm_i8<<<(CDIM / 128) * (HDIM / 128), 256, 0, stream>>>(
      a8, b8, dAs, dBs, c_inp, xa2, acc_se, acc_sce);
  k_final<<<(HDIM + 255) / 256, 256, 0, stream>>>(i_sig, o_sig, g_tanh,
                                                  acc_se, acc_sce, out);
}

// Round 4
// 69.978 us; speedup vs baseline: 1.4736x; 1.0346x over previous
//
#include <hip/hip_runtime.h>
#include <hip/hip_bf16.h>
#include <cstdint>

#define HDIM 2048
#define INDIM 4096
#define CDIM 4096
#define KDIM 2048   // GEMM K = hidden size

typedef __attribute__((ext_vector_type(4))) int int4v;

__device__ __forceinline__ void gload16(const void* g, void* l) {
  __builtin_amdgcn_global_load_lds(
      (const __attribute__((address_space(1))) void*)g,
      (__attribute__((address_space(3))) void*)l, 16, 0, 0);
}

// ---------------- Kernel 1: prep = i8 row-quant (c_input, aW_hh) + GEMVs ------
// Wave-per-row throughout, zero barriers, loads batched 8-deep in explicit
// register arrays for memory ILP (round-3 failure: VGPR=32 -> serialized loads
// -> 16% HBM. This version needs ~90 VGPRs and keeps 8 dwordx4 in flight).
// blocks [0,1536):     quant rows, wave w -> row blockIdx*4+w  (6144 rows)
// blocks [1536,3584):  GEMV virtual rows vr: [0,2048)=i, [2048,4096)=o,
//                      [4096,6144)=g, [6144,8192)=xa2  (f gate dead -> skipped)
__global__ __launch_bounds__(256) void k_prep(
    const float* __restrict__ c_input, const float* __restrict__ aW_hh,
    int8_t* __restrict__ a8, int8_t* __restrict__ b8,
    float* __restrict__ dAs, float* __restrict__ dBs,
    const float* __restrict__ x, const float* __restrict__ h0,
    const float* __restrict__ W_ih, const float* __restrict__ b_ih,
    const float* __restrict__ W_hh, const float* __restrict__ b_hh,
    const float* __restrict__ aW_ih, const float* __restrict__ ab_ih,
    const float* __restrict__ ab_hh,
    float* __restrict__ i_sig, float* __restrict__ o_sig,
    float* __restrict__ g_tanh, float* __restrict__ xa2,
    float* __restrict__ accz) {
  const int t = threadIdx.x;
  const int wid = t >> 6, lane = t & 63;

  if (blockIdx.x < 1536) {
    // ---- i8 row quantization: one wave per 2048-float row ----
    if (blockIdx.x == 0) {
#pragma unroll
      for (int i = 0; i < 16; ++i) accz[i * 256 + t] = 0.f;
    }
    const int row = blockIdx.x * 4 + wid;
    const float* src; int8_t* dst; float* dsc; int r;
    if (row < CDIM) { src = c_input; dst = a8; dsc = dAs; r = row; }
    else            { src = aW_hh;  dst = b8; dsc = dBs; r = row - CDIM; }
    const float4* s4 = (const float4*)(src + (size_t)r * KDIM);
    float4 v[8];
#pragma unroll
    for (int it = 0; it < 8; ++it) v[it] = s4[it * 64 + lane];  // 8 in flight
    float am = 0.f;
#pragma unroll
    for (int it = 0; it < 8; ++it)
      am = fmaxf(am, fmaxf(fmaxf(fabsf(v[it].x), fabsf(v[it].y)),
                           fmaxf(fabsf(v[it].z), fabsf(v[it].w))));
#pragma unroll
    for (int off = 32; off > 0; off >>= 1) am = fmaxf(am, __shfl_xor(am, off));
    am = fmaxf(am, 1e-20f);
    const float inv = 127.0f / am;
    uint32_t* qd = (uint32_t*)(dst + (size_t)r * KDIM);
#pragma unroll
    for (int it = 0; it < 8; ++it) {
      uint32_t p = (uint32_t)(__float2int_rn(v[it].x * inv) & 0xFF)
                 | ((uint32_t)(__float2int_rn(v[it].y * inv) & 0xFF) << 8)
                 | ((uint32_t)(__float2int_rn(v[it].z * inv) & 0xFF) << 16)
                 | ((uint32_t)(__float2int_rn(v[it].w * inv) & 0xFF) << 24);
      qd[it * 64 + lane] = p;
    }
    if (lane == 0) dsc[r] = am * (1.0f / 127.0f);
    return;
  }

  // ---- GEMV: one wave per virtual row ----
  const int vr = (blockIdx.x - 1536) * 4 + wid;
  const int typ = vr >> 11;
  const int h = vr & (HDIM - 1);
  float sum = 0.f;
  const float4* x4 = (const float4*)x;
  if (typ < 3) {
    const int grow = (typ == 0) ? h : (typ == 1) ? (2 * HDIM + h) : (3 * HDIM + h);
    const float4* wr4 = (const float4*)(W_ih + (size_t)grow * INDIM);
#pragma unroll
    for (int g = 0; g < 2; ++g) {  // 2 batches of 8 loads in flight
      float4 w[8];
#pragma unroll
      for (int it = 0; it < 8; ++it) w[it] = wr4[(g * 8 + it) * 64 + lane];
#pragma unroll
      for (int it = 0; it < 8; ++it) {
        float4 xv = x4[(g * 8 + it) * 64 + lane];
        sum += w[it].x * xv.x + w[it].y * xv.y + w[it].z * xv.z + w[it].w * xv.w;
      }
    }
    const float4* wh4 = (const float4*)(W_hh + (size_t)grow * HDIM);
    const float4* h4 = (const float4*)h0;
    {
      float4 w[8];
#pragma unroll
      for (int it = 0; it < 8; ++it) w[it] = wh4[it * 64 + lane];
#pragma unroll
      for (int it = 0; it < 8; ++it) {
        float4 hv = h4[it * 64 + lane];
        sum += w[it].x * hv.x + w[it].y * hv.y + w[it].z * hv.z + w[it].w * hv.w;
      }
    }
#pragma unroll
    for (int off = 32; off > 0; off >>= 1) sum += __shfl_down(sum, off);
    if (lane == 0) {
      float z = sum + b_ih[grow] + b_hh[grow];
      if (typ == 0)      i_sig[h] = 1.f / (1.f + expf(-z));
      else if (typ == 1) o_sig[h] = 1.f / (1.f + expf(-z));
      else               g_tanh[h] = tanhf(z);
    }
  } else {
    const float4* wr4 = (const float4*)(aW_ih + (size_t)h * INDIM);
#pragma unroll
    for (int g = 0; g < 2; ++g) {
      float4 w[8];
#pragma unroll
      for (int it = 0; it < 8; ++it) w[it] = wr4[(g * 8 + it) * 64 + lane];
#pragma unroll
      for (int it = 0; it < 8; ++it) {
        float4 xv = x4[(g * 8 + it) * 64 + lane];
        sum += w[it].x * xv.x + w[it].y * xv.y + w[it].z * xv.z + w[it].w * xv.w;
      }
    }
#pragma unroll
    for (int off = 32; off > 0; off >>= 1) sum += __shfl_down(sum, off);
    if (lane == 0) xa2[h] = sum + ab_ih[h] + ab_hh[h];
  }
}

// ---------------- Kernel 2: i8 MFMA GEMM (LDS double-buffered) + fused epilogue
// alpha_pre[j][h] = dA[j]*dB[h] * sum_k qa[j][k]*qb[h][k]  (i32 exact accum).
// 128x128 tile, BK=128 bytes, 4 waves (2x2 of 64x64), mfma_i32_16x16x64_i8 x2.
// 2-phase double-buffer (T3 minimal): STAGE(next) issued before ds_read+MFMA of
// current; __syncthreads' implicit vmcnt/lgkm drain gives correctness (m97).
// LDS swizzle (rule #21): linear gload_lds dest, source col pre-XORed with
// ((row&7)<<4), ds_read applies the same XOR.
__global__ __launch_bounds__(256, 2) void k_gemm_i8(
    const int8_t* __restrict__ A, const int8_t* __restrict__ B,
    const float* __restrict__ dAs, const float* __restrict__ dBs,
    const float* __restrict__ c_in, const float* __restrict__ xa2,
    float* __restrict__ acc_se, float* __restrict__ acc_sce) {
  __shared__ uint8_t As[2][16384];  // 2 x 128 rows x 128 k-bytes
  __shared__ uint8_t Bs[2][16384];
  const int t = threadIdx.x;
  const int lane = t & 63, wid = t >> 6;
  const int wr = wid >> 1, wc = wid & 1;
  const int l15 = lane & 15, l4 = lane >> 4;
  const int bm = blockIdx.x & 31, bn = blockIdx.x >> 5;
  const int m0 = bm * 128, n0 = bn * 128;

  int4v acc[4][4] = {};

  // staging: per matrix 16 KB/step = 4 x 16B per thread.
  // dest byte d = qq*4096 + t*16 -> row = qq*32 + (t>>3), col = (t&7)*16
  const int trow = t >> 3;
  const int tcol = ((t & 7) * 16) ^ ((trow & 7) << 4);  // pre-swizzled source col
  const int8_t* Arow = A + (size_t)(m0 + trow) * KDIM + tcol;
  const int8_t* Brow = B + (size_t)(n0 + trow) * KDIM + tcol;

#define STAGE(buf, k0)                                                      \
  do {                                                                      \
    _Pragma("unroll")                                                       \
    for (int qq = 0; qq < 4; ++qq) {                                        \
      gload16(Arow + (size_t)qq * 32 * KDIM + (k0), As[buf] + qq * 4096 + t * 16); \
      gload16(Brow + (size_t)qq * 32 * KDIM + (k0), Bs[buf] + qq * 4096 + t * 16); \
    }                                                                       \
  } while (0)

  STAGE(0, 0);
  __syncthreads();  // implicit vmcnt(0) drain -> buf0 ready

  int cur = 0;
  for (int ti = 0; ti < KDIM / 128; ++ti) {  // 16 iterations
    if (ti < KDIM / 128 - 1) STAGE(cur ^ 1, (ti + 1) * 128);
    int4v alo[4], ahi[4], blo[4], bhi[4];
#pragma unroll
    for (int m = 0; m < 4; ++m) {
      const int r = wr * 64 + m * 16 + l15;
      const int swz = (r & 7) << 4;
      alo[m] = *(const int4v*)(As[cur] + r * 128 + ((l4 * 16) ^ swz));
      ahi[m] = *(const int4v*)(As[cur] + r * 128 + ((64 + l4 * 16) ^ swz));
    }
#pragma unroll
    for (int n = 0; n < 4; ++n) {
      const int r = wc * 64 + n * 16 + l15;
      const int swz = (r & 7) << 4;
      blo[n] = *(const int4v*)(Bs[cur] + r * 128 + ((l4 * 16) ^ swz));
      bhi[n] = *(const int4v*)(Bs[cur] + r * 128 + ((64 + l4 * 16) ^ swz));
    }
#pragma unroll
    for (int m = 0; m < 4; ++m)
#pragma unroll
      for (int n = 0; n < 4; ++n) {
        acc[m][n] = __builtin_amdgcn_mfma_i32_16x16x64_i8(alo[m], blo[n], acc[m][n], 0, 0, 0);
        acc[m][n] = __builtin_amdgcn_mfma_i32_16x16x64_i8(ahi[m], bhi[n], acc[m][n], 0, 0, 0);
      }
    __syncthreads();  // drains next-tile staging; all waves done reading cur
    cur ^= 1;
  }
#undef STAGE

  // epilogue: D layout col = lane&15, row = (lane>>4)*4 + reg  [m89-verified,
  // dtype/shape-independent per m121-m128]
#pragma unroll
  for (int n = 0; n < 4; ++n) {
    const int hcol = n0 + wc * 64 + n * 16 + l15;
    const float xa = xa2[hcol];
    const float db = dBs[hcol];
    float se = 0.f, sce = 0.f;
#pragma unroll
    for (int m = 0; m < 4; ++m) {
      const int jbase = m0 + wr * 64 + m * 16 + l4 * 4;
#pragma unroll
      for (int rr = 0; rr < 4; ++rr) {
        const float sc = dAs[jbase + rr] * db;
        float z = (float)acc[m][n][rr] * sc + xa;
        float s = 1.f / (1.f + __expf(-z));
        float e = __expf(s);
        se += e;
        sce += c_in[(size_t)(jbase + rr) * HDIM + hcol] * e;
      }
    }
    se += __shfl_xor(se, 16); se += __shfl_xor(se, 32);
    sce += __shfl_xor(sce, 16); sce += __shfl_xor(sce, 32);
    if (l4 == 0) {
      atomicAdd(&acc_se[hcol], se);
      atomicAdd(&acc_sce[hcol], sce);
    }
  }
}

// ---------------- Kernel 3: finalize ------------------------------------------
__global__ __launch_bounds__(256) void k_final(
    const float* __restrict__ i_sig, const float* __restrict__ o_sig,
    const float* __restrict__ g_tanh, const float* __restrict__ acc_se,
    const float* __restrict__ acc_sce, float* __restrict__ out) {
  int h = blockIdx.x * 256 + threadIdx.x;
  if (h >= HDIM) return;
  float wi = expf(i_sig[h]);
  float tot = acc_se[h] + wi;
  float c1 = (acc_sce[h] + g_tanh[h] * wi) / tot;
  float h1 = o_sig[h] * tanhf(c1);
  out[h] = h1;
  out[HDIM + h] = c1;
}

extern "C" void kernel_launch(void* const* d_in, const int* in_sizes, int n_in,
                              void* d_out, int out_size, void* d_ws, size_t ws_size,
                              hipStream_t stream) {
  const float* x     = (const float*)d_in[0];
  const float* c_inp = (const float*)d_in[1];
  const float* h0    = (const float*)d_in[2];
  // d_in[3] = c0: unused by the reference output
  const float* W_ih  = (const float*)d_in[4];
  const float* b_ih  = (const float*)d_in[5];
  const float* W_hh  = (const float*)d_in[6];
  const float* b_hh  = (const float*)d_in[7];
  const float* aW_ih = (const float*)d_in[8];
  const float* ab_ih = (const float*)d_in[9];
  const float* aW_hh = (const float*)d_in[10];
  const float* ab_hh = (const float*)d_in[11];
  float* out = (float*)d_out;

  char* ws = (char*)d_ws;
  int8_t* a8 = (int8_t*)ws;                          // 8 MB i8 c_input
  int8_t* b8 = a8 + (size_t)CDIM * KDIM;             // 4 MB i8 aW_hh
  float* dAs = (float*)(b8 + (size_t)HDIM * KDIM);   // 16 KB row scales A
  float* dBs = dAs + CDIM;                           // 8 KB row scales B
  float* fb  = dBs + HDIM;
  float* i_sig   = fb;
  float* o_sig   = fb + HDIM;
  float* g_tanh  = fb + 2 * HDIM;
  float* xa2     = fb + 3 * HDIM;
  float* acc_se  = fb + 4 * HDIM;   // acc_se/acc_sce contiguous: zeroed together
  float* acc_sce = fb + 5 * HDIM;

  // blocks: 1536 quant (wave-per-row, 6144 rows) + 2048 gemv (wave-per-vrow)
  k_prep<<<1536 + 2048, 256, 0, stream>>>(
      c_inp, aW_hh, a8, b8, dAs, dBs,
      x, h0, W_ih, b_ih, W_hh, b_hh, aW_ih, ab_ih, ab_hh,
      i_sig, o_sig, g_tanh, xa2, acc_se);
  k_gemm_i8<<<(CDIM / 128) * (HDIM / 128), 256, 0, stream>>>(
      a8, b8, dAs, dBs, c_inp, xa2, acc_se, acc_sce);
  k_final<<<(HDIM + 255) / 256, 256, 0, stream>>>(i_sig, o_sig, g_tanh,
                                                  acc_se, acc_sce, out);
}

// Round 5
// 65.638 us; speedup vs baseline: 1.5711x; 1.0661x over previous
//
#include <hip/hip_runtime.h>
#include <hip/hip_bf16.h>
#include <cstdint>

#define HDIM 2048
#define INDIM 4096
#define CDIM 4096
#define KDIM 2048   // GEMM K = hidden size

typedef __attribute__((ext_vector_type(4))) int int4v;

__device__ __forceinline__ void gload16(const void* g, void* l) {
  __builtin_amdgcn_global_load_lds(
      (const __attribute__((address_space(1))) void*)g,
      (__attribute__((address_space(3))) void*)l, 16, 0, 0);
}

// ---------------- Kernel 1: i8 row-quant (c_input, aW_hh) + xa2 GEMV ----------
// Only the work the GEMM depends on. Gate GEMVs moved into k2 (overlap).
// blocks [0,1536):    quant rows, wave w -> row blockIdx*4+w  (6144 rows)
// blocks [1536,2048): xa2[h] = x @ aW_ih[h] + ab_ih[h] + ab_hh[h]
__global__ __launch_bounds__(256) void k_quant_xa2(
    const float* __restrict__ c_input, const float* __restrict__ aW_hh,
    int8_t* __restrict__ a8, int8_t* __restrict__ b8,
    float* __restrict__ dAs, float* __restrict__ dBs,
    const float* __restrict__ x,
    const float* __restrict__ aW_ih, const float* __restrict__ ab_ih,
    const float* __restrict__ ab_hh,
    float* __restrict__ xa2, float* __restrict__ accz) {
  const int t = threadIdx.x;
  const int wid = t >> 6, lane = t & 63;

  if (blockIdx.x < 1536) {
    if (blockIdx.x == 0) {  // zero acc_se/acc_sce (4096 floats) every launch
#pragma unroll
      for (int i = 0; i < 16; ++i) accz[i * 256 + t] = 0.f;
    }
    const int row = blockIdx.x * 4 + wid;
    const float* src; int8_t* dst; float* dsc; int r;
    if (row < CDIM) { src = c_input; dst = a8; dsc = dAs; r = row; }
    else            { src = aW_hh;  dst = b8; dsc = dBs; r = row - CDIM; }
    const float4* s4 = (const float4*)(src + (size_t)r * KDIM);
    float4 v[8];
#pragma unroll
    for (int it = 0; it < 8; ++it) v[it] = s4[it * 64 + lane];
    float am = 0.f;
#pragma unroll
    for (int it = 0; it < 8; ++it)
      am = fmaxf(am, fmaxf(fmaxf(fabsf(v[it].x), fabsf(v[it].y)),
                           fmaxf(fabsf(v[it].z), fabsf(v[it].w))));
#pragma unroll
    for (int off = 32; off > 0; off >>= 1) am = fmaxf(am, __shfl_xor(am, off));
    am = fmaxf(am, 1e-20f);
    const float inv = 127.0f / am;
    uint32_t* qd = (uint32_t*)(dst + (size_t)r * KDIM);
#pragma unroll
    for (int it = 0; it < 8; ++it) {
      uint32_t p = (uint32_t)(__float2int_rn(v[it].x * inv) & 0xFF)
                 | ((uint32_t)(__float2int_rn(v[it].y * inv) & 0xFF) << 8)
                 | ((uint32_t)(__float2int_rn(v[it].z * inv) & 0xFF) << 16)
                 | ((uint32_t)(__float2int_rn(v[it].w * inv) & 0xFF) << 24);
      qd[it * 64 + lane] = p;
    }
    if (lane == 0) dsc[r] = am * (1.0f / 127.0f);
    return;
  }

  // ---- xa2 GEMV: one wave per h ----
  const int h = (blockIdx.x - 1536) * 4 + wid;
  const float4* x4 = (const float4*)x;
  const float4* wr4 = (const float4*)(aW_ih + (size_t)h * INDIM);
  float sum = 0.f;
#pragma unroll
  for (int g = 0; g < 2; ++g) {
    float4 w[8];
#pragma unroll
    for (int it = 0; it < 8; ++it) w[it] = wr4[(g * 8 + it) * 64 + lane];
#pragma unroll
    for (int it = 0; it < 8; ++it) {
      float4 xv = x4[(g * 8 + it) * 64 + lane];
      sum += w[it].x * xv.x + w[it].y * xv.y + w[it].z * xv.z + w[it].w * xv.w;
    }
  }
#pragma unroll
  for (int off = 32; off > 0; off >>= 1) sum += __shfl_down(sum, off);
  if (lane == 0) xa2[h] = sum + ab_ih[h] + ab_hh[h];
}

// ---------------- Kernel 2: fat kernel = i8 GEMM  ||  gate GEMVs --------------
// blocks [0,512):    GEMM 128x128 tile, BK=64 double-buffered (32 KB LDS so
//                    GEMV blocks co-reside; 4 blocks/CU via launch_bounds).
//                    mfma_i32_16x16x64_i8, i32 exact accum, fused
//                    sigmoid/exp/column-reduce epilogue with atomics.
// blocks [512,2048): gate GEMVs (i,o,g): HBM streaming overlaps GEMM compute
//                    (separate pipes, m114). f gate dead -> skipped.
// LDS swizzle (rule #21, BK=64): linear gload_lds dest, source col pre-XORed
// with ((row&3)<<4), ds_read applies the same XOR -> 2-way residual (free).
__global__ __launch_bounds__(256, 4) void k_gemm_gemv(
    const int8_t* __restrict__ A, const int8_t* __restrict__ B,
    const float* __restrict__ dAs, const float* __restrict__ dBs,
    const float* __restrict__ c_in, const float* __restrict__ xa2,
    float* __restrict__ acc_se, float* __restrict__ acc_sce,
    const float* __restrict__ x, const float* __restrict__ h0,
    const float* __restrict__ W_ih, const float* __restrict__ b_ih,
    const float* __restrict__ W_hh, const float* __restrict__ b_hh,
    float* __restrict__ i_sig, float* __restrict__ o_sig,
    float* __restrict__ g_tanh) {
  __shared__ uint8_t As[2][8192];  // 128 rows x 64 k-bytes, double-buffered
  __shared__ uint8_t Bs[2][8192];
  const int t = threadIdx.x;
  const int lane = t & 63, wid = t >> 6;

  if (blockIdx.x < 512) {
    // ================= GEMM path =================
    const int wr = wid >> 1, wc = wid & 1;
    const int l15 = lane & 15, l4 = lane >> 4;
    const int bm = blockIdx.x & 31, bn = blockIdx.x >> 5;
    const int m0 = bm * 128, n0 = bn * 128;

    int4v acc[4][4] = {};

    // staging: per matrix 8 KB/step = 2 x 16B per thread.
    // dest byte d = qq*4096 + t*16 -> row = qq*64 + (t>>2), col = (t&3)*16
    const int trow = t >> 2;
    const int tcol = ((t & 3) * 16) ^ ((trow & 3) << 4);  // pre-swizzled src col
    const int8_t* Arow = A + (size_t)(m0 + trow) * KDIM + tcol;
    const int8_t* Brow = B + (size_t)(n0 + trow) * KDIM + tcol;

#define STAGE(buf, k0)                                                          \
    do {                                                                        \
      _Pragma("unroll")                                                         \
      for (int qq = 0; qq < 2; ++qq) {                                          \
        gload16(Arow + (size_t)qq * 64 * KDIM + (k0), As[buf] + qq * 4096 + t * 16); \
        gload16(Brow + (size_t)qq * 64 * KDIM + (k0), Bs[buf] + qq * 4096 + t * 16); \
      }                                                                         \
    } while (0)

    STAGE(0, 0);
    __syncthreads();  // implicit vmcnt(0) drain -> buf0 ready

    int cur = 0;
    for (int ti = 0; ti < KDIM / 64; ++ti) {  // 32 iterations
      if (ti < KDIM / 64 - 1) STAGE(cur ^ 1, (ti + 1) * 64);
      int4v af[4], bfr[4];
#pragma unroll
      for (int m = 0; m < 4; ++m) {
        const int r = wr * 64 + m * 16 + l15;
        af[m] = *(const int4v*)(As[cur] + r * 64 + ((l4 * 16) ^ ((r & 3) << 4)));
      }
#pragma unroll
      for (int n = 0; n < 4; ++n) {
        const int r = wc * 64 + n * 16 + l15;
        bfr[n] = *(const int4v*)(Bs[cur] + r * 64 + ((l4 * 16) ^ ((r & 3) << 4)));
      }
#pragma unroll
      for (int m = 0; m < 4; ++m)
#pragma unroll
        for (int n = 0; n < 4; ++n)
          acc[m][n] = __builtin_amdgcn_mfma_i32_16x16x64_i8(af[m], bfr[n], acc[m][n], 0, 0, 0);
      __syncthreads();  // reads of cur done; staging into cur^1 drained
      cur ^= 1;
    }
#undef STAGE

    // epilogue: D layout col = lane&15, row = (lane>>4)*4 + reg [m89-verified]
#pragma unroll
    for (int n = 0; n < 4; ++n) {
      const int hcol = n0 + wc * 64 + n * 16 + l15;
      const float xa = xa2[hcol];
      const float db = dBs[hcol];
      float se = 0.f, sce = 0.f;
#pragma unroll
      for (int m = 0; m < 4; ++m) {
        const int jbase = m0 + wr * 64 + m * 16 + l4 * 4;
#pragma unroll
        for (int rr = 0; rr < 4; ++rr) {
          const float sc = dAs[jbase + rr] * db;
          float z = (float)acc[m][n][rr] * sc + xa;
          float s = 1.f / (1.f + __expf(-z));
          float e = __expf(s);
          se += e;
          sce += c_in[(size_t)(jbase + rr) * HDIM + hcol] * e;
        }
      }
      se += __shfl_xor(se, 16); se += __shfl_xor(se, 32);
      sce += __shfl_xor(sce, 16); sce += __shfl_xor(sce, 32);
      if (l4 == 0) {
        atomicAdd(&acc_se[hcol], se);
        atomicAdd(&acc_sce[hcol], sce);
      }
    }
    return;
  }

  // ================= gate GEMV path (i, o, g) =================
  const int vr = (blockIdx.x - 512) * 4 + wid;  // [0, 6144)
  const int typ = vr >> 11;                     // 0=i, 1=o, 2=g
  const int h = vr & (HDIM - 1);
  const int grow = (typ == 0) ? h : (typ == 1) ? (2 * HDIM + h) : (3 * HDIM + h);
  float sum = 0.f;
  const float4* x4 = (const float4*)x;
  const float4* wr4 = (const float4*)(W_ih + (size_t)grow * INDIM);
#pragma unroll
  for (int g = 0; g < 2; ++g) {  // 2 batches of 8 loads
    float4 w[8];
#pragma unroll
    for (int it = 0; it < 8; ++it) w[it] = wr4[(g * 8 + it) * 64 + lane];
#pragma unroll
    for (int it = 0; it < 8; ++it) {
      float4 xv = x4[(g * 8 + it) * 64 + lane];
      sum += w[it].x * xv.x + w[it].y * xv.y + w[it].z * xv.z + w[it].w * xv.w;
    }
  }
  {
    const float4* wh4 = (const float4*)(W_hh + (size_t)grow * HDIM);
    const float4* h4 = (const float4*)h0;
    float4 w[8];
#pragma unroll
    for (int it = 0; it < 8; ++it) w[it] = wh4[it * 64 + lane];
#pragma unroll
    for (int it = 0; it < 8; ++it) {
      float4 hv = h4[it * 64 + lane];
      sum += w[it].x * hv.x + w[it].y * hv.y + w[it].z * hv.z + w[it].w * hv.w;
    }
  }
#pragma unroll
  for (int off = 32; off > 0; off >>= 1) sum += __shfl_down(sum, off);
  if (lane == 0) {
    float z = sum + b_ih[grow] + b_hh[grow];
    if (typ == 0)      i_sig[h] = 1.f / (1.f + expf(-z));
    else if (typ == 1) o_sig[h] = 1.f / (1.f + expf(-z));
    else               g_tanh[h] = tanhf(z);
  }
}

// ---------------- Kernel 3: finalize ------------------------------------------
__global__ __launch_bounds__(256) void k_final(
    const float* __restrict__ i_sig, const float* __restrict__ o_sig,
    const float* __restrict__ g_tanh, const float* __restrict__ acc_se,
    const float* __restrict__ acc_sce, float* __restrict__ out) {
  int h = blockIdx.x * 256 + threadIdx.x;
  if (h >= HDIM) return;
  float wi = expf(i_sig[h]);
  float tot = acc_se[h] + wi;
  float c1 = (acc_sce[h] + g_tanh[h] * wi) / tot;
  float h1 = o_sig[h] * tanhf(c1);
  out[h] = h1;
  out[HDIM + h] = c1;
}

extern "C" void kernel_launch(void* const* d_in, const int* in_sizes, int n_in,
                              void* d_out, int out_size, void* d_ws, size_t ws_size,
                              hipStream_t stream) {
  const float* x     = (const float*)d_in[0];
  const float* c_inp = (const float*)d_in[1];
  const float* h0    = (const float*)d_in[2];
  // d_in[3] = c0: unused by the reference output
  const float* W_ih  = (const float*)d_in[4];
  const float* b_ih  = (const float*)d_in[5];
  const float* W_hh  = (const float*)d_in[6];
  const float* b_hh  = (const float*)d_in[7];
  const float* aW_ih = (const float*)d_in[8];
  const float* ab_ih = (const float*)d_in[9];
  const float* aW_hh = (const float*)d_in[10];
  const float* ab_hh = (const float*)d_in[11];
  float* out = (float*)d_out;

  char* ws = (char*)d_ws;
  int8_t* a8 = (int8_t*)ws;                          // 8 MB i8 c_input
  int8_t* b8 = a8 + (size_t)CDIM * KDIM;             // 4 MB i8 aW_hh
  float* dAs = (float*)(b8 + (size_t)HDIM * KDIM);   // 16 KB row scales A
  float* dBs = dAs + CDIM;                           // 8 KB row scales B
  float* fb  = dBs + HDIM;
  float* i_sig   = fb;
  float* o_sig   = fb + HDIM;
  float* g_tanh  = fb + 2 * HDIM;
  float* xa2     = fb + 3 * HDIM;
  float* acc_se  = fb + 4 * HDIM;   // acc_se/acc_sce contiguous: zeroed together
  float* acc_sce = fb + 5 * HDIM;

  // k1: 1536 quant blocks (6144 rows) + 512 xa2-GEMV blocks
  k_quant_xa2<<<2048, 256, 0, stream>>>(
      c_inp, aW_hh, a8, b8, dAs, dBs, x, aW_ih, ab_ih, ab_hh, xa2, acc_se);
  // k2: 512 GEMM blocks (first -> scheduled first) + 1536 gate-GEMV blocks
  k_gemm_gemv<<<512 + 1536, 256, 0, stream>>>(
      a8, b8, dAs, dBs, c_inp, xa2, acc_se, acc_sce,
      x, h0, W_ih, b_ih, W_hh, b_hh, i_sig, o_sig, g_tanh);
  k_final<<<(HDIM + 255) / 256, 256, 0, stream>>>(i_sig, o_sig, g_tanh,
                                                  acc_se, acc_sce, out);
}